// Round 1
// baseline (357.790 us; speedup 1.0000x reference)
//
#include <hip/hip_runtime.h>
#include <hip/hip_bf16.h>

#define D 128          // D_IN == D_OUT
#define KDIM 256       // concatenated K = 2*D
#define ROWS 32        // dst rows per fused block
#define LDK 264        // 256 + 8 bf16 pad
#define MAX_BE 768     // LDS edge-list capacity per fused block (Poisson(512)+11sigma)

#define CSH 9          // coarse bucket = 512 dst nodes
#define CWID 512
#define GFILL 256      // coarse-partition blocks
#define FCHUNK 6400    // LDS sort capacity per fill block (chunk = 6250)
#define SB_CAP 10240   // fine-sort capacity per coarse bucket (mean 8163, +23 sigma)

typedef __attribute__((ext_vector_type(8))) short short8;
typedef __attribute__((ext_vector_type(4))) float floatx4;

static __device__ __forceinline__ ushort f2bf(float x) {
    __hip_bfloat16 h = __float2bfloat16(x);
    return __builtin_bit_cast(ushort, h);
}

// ---------------------------------------------------------------------------
// Fused prep + coarse histogram.
// blocks [0, nbF):          feat fp32 -> bf16 (packed)
// blocks [nbF, nbF+128):    Wc = [W_self | W_neigh] bf16
// blocks [nbF+128, +GFILL): per-chunk LDS histogram over 196 coarse buckets
//                           -> histA[c][block]  (no global atomics)
// ---------------------------------------------------------------------------
__global__ void k_prep_hist(const float* __restrict__ feat,
                            const float* __restrict__ Wself,
                            const float* __restrict__ Wneigh,
                            const int* __restrict__ dst,
                            ushort* __restrict__ feat_b,
                            ushort* __restrict__ Wc,
                            int* __restrict__ histA,
                            int nbF, int nFeat8, int E, int chunk, int nc) {
    __shared__ int sh[CWID];
    int b = blockIdx.x;
    if (b < nbF) {
        int i = b * 256 + threadIdx.x;      // one thread per 8 elems
        if (i < nFeat8) {
            const float4* f4 = (const float4*)feat;
            float4 f0 = f4[(size_t)i * 2];
            float4 f1 = f4[(size_t)i * 2 + 1];
            ushort o[8];
            o[0] = f2bf(f0.x); o[1] = f2bf(f0.y);
            o[2] = f2bf(f0.z); o[3] = f2bf(f0.w);
            o[4] = f2bf(f1.x); o[5] = f2bf(f1.y);
            o[6] = f2bf(f1.z); o[7] = f2bf(f1.w);
            *(short8*)(feat_b + (size_t)i * 8) = *(short8*)o;
        }
    } else if (b < nbF + 128) {
        int idx = (b - nbF) * 256 + threadIdx.x;   // < 128*256
        int j = idx >> 8;
        int k = idx & 255;
        float v = (k < D) ? Wself[j * D + k] : Wneigh[j * D + (k - D)];
        Wc[idx] = f2bf(v);
    } else {
        int b2 = b - nbF - 128;
        int beg = b2 * chunk;
        int end = min(E, beg + chunk);
        for (int i = threadIdx.x; i < nc; i += 256) sh[i] = 0;
        __syncthreads();
        for (int i = beg + threadIdx.x; i < end; i += 256)
            atomicAdd(&sh[((unsigned)dst[i]) >> CSH], 1);
        __syncthreads();
        for (int c = threadIdx.x; c < nc; c += 256) histA[c * GFILL + b2] = sh[c];
    }
}

// ---------------------------------------------------------------------------
// One flat exclusive scan of histA[nc*GFILL] (c-major) -> per-(bucket,block)
// global bases in place, plus coarsePtr[c] (bucket starts).
// ---------------------------------------------------------------------------
__global__ __launch_bounds__(1024) void k_scan(int* __restrict__ histA,
                                               int* __restrict__ coarsePtr,
                                               int total, int E) {
    __shared__ int wsum[16], woff[16];
    int t = threadIdx.x;
    int per = (total + 1023) / 1024;   // 49 for nc=196
    int base = t * per;
    int tsum = 0;
    for (int j = 0; j < per; j++) {
        int idx = base + j;
        if (idx < total) tsum += histA[idx];
    }
    int lane = t & 63, wv = t >> 6;
    int v = tsum;
    for (int d = 1; d < 64; d <<= 1) {
        int o = __shfl_up(v, d, 64);
        if (lane >= d) v += o;
    }
    if (lane == 63) wsum[wv] = v;
    __syncthreads();
    if (t == 0) {
        int run = 0;
        for (int i = 0; i < 16; i++) { woff[i] = run; run += wsum[i]; }
    }
    __syncthreads();
    int run = (v - tsum) + woff[wv];   // exclusive prefix for this thread
    for (int j = 0; j < per; j++) {
        int idx = base + j;
        if (idx < total) {
            int c = histA[idx];
            histA[idx] = run;
            if ((idx & (GFILL - 1)) == 0) coarsePtr[idx / GFILL] = run;
            run += c;
        }
    }
    if (t == 0) coarsePtr[total / GFILL] = E;
}

// ---------------------------------------------------------------------------
// Coarse partition: LDS counting-sort of each 6250-edge chunk into 196 coarse
// buckets, written out as contiguous runs (coalesced). No global atomics.
// Packed: (src << 9) | (dst & 511).
// ---------------------------------------------------------------------------
__global__ __launch_bounds__(256) void k_fillA(const int* __restrict__ src,
                                               const int* __restrict__ dst,
                                               const int* __restrict__ histA,
                                               uint* __restrict__ epA,
                                               int E, int chunk, int nc) {
    __shared__ int sh[200], soffs[200], scur[200];
    __shared__ uint sbuf[FCHUNK];
    int b2 = blockIdx.x;
    int beg = b2 * chunk;
    int end = min(E, beg + chunk);
    int cntB = end - beg;
    int tid = threadIdx.x;
    for (int i = tid; i < nc; i += 256) sh[i] = 0;
    __syncthreads();
    for (int i = beg + tid; i < end; i += 256)
        atomicAdd(&sh[((unsigned)dst[i]) >> CSH], 1);
    __syncthreads();
    if (tid == 0) {
        int run = 0;
        for (int c = 0; c < nc; c++) { soffs[c] = run; run += sh[c]; }
    }
    __syncthreads();
    if (tid < nc) scur[tid] = soffs[tid];
    __syncthreads();
    for (int i = beg + tid; i < end; i += 256) {
        int dv = dst[i];
        int sv = src[i];
        int c = ((unsigned)dv) >> CSH;
        int slot = atomicAdd(&scur[c], 1);
        sbuf[slot] = ((uint)sv << CSH) | (uint)(dv & (CWID - 1));
    }
    __syncthreads();
    int w = tid >> 6, lane = tid & 63;
    for (int c = w; c < nc; c += 4) {
        int s0 = soffs[c];
        int s1 = (c + 1 < nc) ? soffs[c + 1] : cntB;
        int gb = histA[c * GFILL + b2];
        for (int i = s0 + lane; i < s1; i += 64) epA[gb + (i - s0)] = sbuf[i];
    }
}

// ---------------------------------------------------------------------------
// Fine partition: per coarse bucket (~8k edges), counting-sort by dst node
// (512-way) in LDS -> per-node CSR (nodeptr) + node-grouped src list (ep).
// All reads/writes coalesced.
// ---------------------------------------------------------------------------
__global__ __launch_bounds__(256) void k_fineB(const uint* __restrict__ epA,
                                               const int* __restrict__ coarsePtr,
                                               uint* __restrict__ ep,
                                               int* __restrict__ nodeptr,
                                               int nc) {
    __shared__ uint sbuf[SB_CAP];
    __shared__ int h[CWID], cur[CWID];
    __shared__ int wq[4];
    int c = blockIdx.x;
    int base = coarsePtr[c];
    int cnt = min(coarsePtr[c + 1] - base, SB_CAP);
    int tid = threadIdx.x;
    int i2 = tid * 2;
    h[i2] = 0; h[i2 + 1] = 0;
    __syncthreads();
    for (int i = tid; i < cnt; i += 256)
        atomicAdd(&h[epA[base + i] & (CWID - 1)], 1);
    __syncthreads();
    // exclusive scan of 512 counters, 2 per thread
    int a = h[i2], bb = h[i2 + 1];
    int pair = a + bb;
    int lane = tid & 63, wv = tid >> 6;
    int v = pair;
    for (int d = 1; d < 64; d <<= 1) {
        int o = __shfl_up(v, d, 64);
        if (lane >= d) v += o;
    }
    if (lane == 63) wq[wv] = v;
    __syncthreads();
    if (tid == 0) {
        int run = 0;
        for (int j = 0; j < 4; j++) { int s = wq[j]; wq[j] = run; run += s; }
    }
    __syncthreads();
    int excl = (v - pair) + wq[wv];
    h[i2] = excl;                 // in-place: h becomes offsets
    h[i2 + 1] = excl + a;
    cur[i2] = excl;
    cur[i2 + 1] = excl + a;
    nodeptr[c * CWID + i2] = base + excl;
    nodeptr[c * CWID + i2 + 1] = base + excl + a;
    if (tid == 0 && c + 1 == nc) nodeptr[(c + 1) * CWID] = coarsePtr[c + 1];
    __syncthreads();
    for (int i = tid; i < cnt; i += 256) {
        uint p = epA[base + i];
        int n = p & (CWID - 1);
        int slot = atomicAdd(&cur[n], 1);
        sbuf[slot] = p >> CSH;    // pure src id, node-grouped
    }
    __syncthreads();
    for (int i = tid; i < cnt; i += 256) ep[base + i] = sbuf[i];
}

// ---------------------------------------------------------------------------
// Fused: CSR-driven gather-mean + GEMM.  Block = 256 thr, tile 32 x 128.
// Phase A: stage self bf16 rows + copy node-grouped elist (no sort needed).
// Phase B: per-node gather-mean, 16-deep load batches (128 B in flight/thr).
// Phase C: MFMA 16x16x32.
// LDS: 16896 + 3072 + 256 = 20224 B -> 8 blocks/CU.
// ---------------------------------------------------------------------------
__global__ __launch_bounds__(256, 8) void sage_fused(
        const ushort* __restrict__ feat_b,
        const int* __restrict__ nodeptr,
        const uint* __restrict__ ep,
        const short* __restrict__ Wc,
        float* __restrict__ out,
        int N) {
    __shared__ ushort X[ROWS * LDK];
    __shared__ uint elist[MAX_BE];
    __shared__ int counts[32], offs[32];

    const int tid = threadIdx.x;
    const int b = blockIdx.x;
    const int v0 = b * ROWS;

    int e0 = nodeptr[v0];
    int cnt = min(nodeptr[v0 + ROWS] - e0, MAX_BE);

    if (tid < 32) {
        int np0 = nodeptr[v0 + tid];
        int np1 = nodeptr[v0 + tid + 1];
        offs[tid] = np0 - e0;
        counts[tid] = np1 - np0;
    }

    // ---- Phase A: self rows, 16 B per load, 2 loads/thread ----
#pragma unroll
    for (int i = 0; i < 2; i++) {
        int idx = tid + i * 256;       // 0..511
        int r = idx >> 4;              // row 0..31
        int c = idx & 15;              // 16B chunk 0..15
        int v = v0 + r;
        short8 f = {0, 0, 0, 0, 0, 0, 0, 0};
        if (v < N) f = *(const short8*)(feat_b + (size_t)v * D + c * 8);
        *(short8*)&X[r * LDK + c * 8] = f;
    }
    // elist copy (already node-grouped by k_fineB)
    for (int i = tid; i < cnt; i += 256) elist[i] = ep[e0 + i];
    __syncthreads();

    // ---- Phase B: neighbor mean (bf16 gather, fp32 accumulate) ----
    {
        const int ln = tid >> 5;       // node slot 0..7
        const int q = tid & 31;        // 4-elem chunk 0..31
        for (int g = 0; g < 4; g++) {
            int r = g * 8 + ln;
            int v = v0 + r;
            float4 acc = make_float4(0.f, 0.f, 0.f, 0.f);
            float rd = 0.f;
            if (v < N) {
                int eb = offs[r];
                int dg = counts[r];
                dg = min(dg, max(cnt - eb, 0));   // clamp (prob ~0 path)
                rd = (dg > 0) ? 1.0f / (float)dg : 0.f;
                int e = 0;
                for (; e + 15 < dg; e += 16) {
                    uint2 pa[8], pb[8];
#pragma unroll
                    for (int j = 0; j < 8; j++) {
                        uint u = elist[eb + e + j];
                        pa[j] = *(const uint2*)(feat_b + (size_t)u * D + q * 4);
                    }
#pragma unroll
                    for (int j = 0; j < 8; j++) {
                        uint u = elist[eb + e + 8 + j];
                        pb[j] = *(const uint2*)(feat_b + (size_t)u * D + q * 4);
                    }
#pragma unroll
                    for (int j = 0; j < 8; j++) {
                        acc.x += __uint_as_float(pa[j].x << 16);
                        acc.y += __uint_as_float(pa[j].x & 0xffff0000u);
                        acc.z += __uint_as_float(pa[j].y << 16);
                        acc.w += __uint_as_float(pa[j].y & 0xffff0000u);
                    }
#pragma unroll
                    for (int j = 0; j < 8; j++) {
                        acc.x += __uint_as_float(pb[j].x << 16);
                        acc.y += __uint_as_float(pb[j].x & 0xffff0000u);
                        acc.z += __uint_as_float(pb[j].y << 16);
                        acc.w += __uint_as_float(pb[j].y & 0xffff0000u);
                    }
                }
                if (e + 7 < dg) {
                    uint2 pa[8];
#pragma unroll
                    for (int j = 0; j < 8; j++) {
                        uint u = elist[eb + e + j];
                        pa[j] = *(const uint2*)(feat_b + (size_t)u * D + q * 4);
                    }
#pragma unroll
                    for (int j = 0; j < 8; j++) {
                        acc.x += __uint_as_float(pa[j].x << 16);
                        acc.y += __uint_as_float(pa[j].x & 0xffff0000u);
                        acc.z += __uint_as_float(pa[j].y << 16);
                        acc.w += __uint_as_float(pa[j].y & 0xffff0000u);
                    }
                    e += 8;
                }
                for (; e + 1 < dg; e += 2) {
                    uint ua = elist[eb + e], ub = elist[eb + e + 1];
                    uint2 pa = *(const uint2*)(feat_b + (size_t)ua * D + q * 4);
                    uint2 pb = *(const uint2*)(feat_b + (size_t)ub * D + q * 4);
                    acc.x += __uint_as_float(pa.x << 16) + __uint_as_float(pb.x << 16);
                    acc.y += __uint_as_float(pa.x & 0xffff0000u) + __uint_as_float(pb.x & 0xffff0000u);
                    acc.z += __uint_as_float(pa.y << 16) + __uint_as_float(pb.y << 16);
                    acc.w += __uint_as_float(pa.y & 0xffff0000u) + __uint_as_float(pb.y & 0xffff0000u);
                }
                if (e < dg) {
                    uint u = elist[eb + e];
                    uint2 pa = *(const uint2*)(feat_b + (size_t)u * D + q * 4);
                    acc.x += __uint_as_float(pa.x << 16);
                    acc.y += __uint_as_float(pa.x & 0xffff0000u);
                    acc.z += __uint_as_float(pa.y << 16);
                    acc.w += __uint_as_float(pa.y & 0xffff0000u);
                }
            }
            ushort o[4];
            o[0] = f2bf(acc.x * rd);
            o[1] = f2bf(acc.y * rd);
            o[2] = f2bf(acc.z * rd);
            o[3] = f2bf(acc.w * rd);
            *(ushort2*)&X[r * LDK + D + q * 4] = *(ushort2*)&o[0];
            *(ushort2*)&X[r * LDK + D + q * 4 + 2] = *(ushort2*)&o[2];
        }
    }
    __syncthreads();

    // ---- Phase C: MFMA ----
    const int lane = tid & 63;
    const int w = tid >> 6;
    const int col = lane & 15;
    const int quad = lane >> 4;
    const int rowBase = (w & 1) * 16;
    const int ctBase = (w >> 1) * 4;

    floatx4 o[4];
#pragma unroll
    for (int ct = 0; ct < 4; ct++) o[ct] = (floatx4){0.f, 0.f, 0.f, 0.f};

#pragma unroll
    for (int kt = 0; kt < 8; kt++) {
        int k0 = kt * 32;
        short8 a = *(const short8*)&X[(rowBase + col) * LDK + k0 + quad * 8];
#pragma unroll
        for (int ct = 0; ct < 4; ct++) {
            short8 bfr = *(const short8*)(Wc + ((ctBase + ct) * 16 + col) * KDIM + k0 + quad * 8);
            o[ct] = __builtin_amdgcn_mfma_f32_16x16x32_bf16(a, bfr, o[ct], 0, 0, 0);
        }
    }

    int vbase = v0 + rowBase + quad * 4;
#pragma unroll
    for (int ct = 0; ct < 4; ct++) {
#pragma unroll
        for (int r = 0; r < 4; r++) {
            int v = vbase + r;
            if (v < N) out[(size_t)v * D + (ctBase + ct) * 16 + col] = o[ct][r];
        }
    }
}

// ---------------------------------------------------------------------------
extern "C" void kernel_launch(void* const* d_in, const int* in_sizes, int n_in,
                              void* d_out, int out_size, void* d_ws, size_t ws_size,
                              hipStream_t stream) {
    const float* feat   = (const float*)d_in[0];
    const int*   src    = (const int*)d_in[1];
    const int*   dst    = (const int*)d_in[2];
    const float* Wself  = (const float*)d_in[3];
    const float* Wneigh = (const float*)d_in[4];
    float* out = (float*)d_out;

    const int N = in_sizes[0] / D;               // 100000
    const int E = in_sizes[1];                   // 1600000
    const int nb = (N + ROWS - 1) / ROWS;        // 3125 fused blocks
    const int nc = (N + CWID - 1) / CWID;        // 196 coarse buckets
    const int chunk = (E + GFILL - 1) / GFILL;   // 6250 (<= FCHUNK)
    const int total = nc * GFILL;                // 50176

    // ---- workspace carve-up ----
    char* ws = (char*)d_ws;
    size_t off = 0;
    auto carve = [&](size_t bytes) {
        char* p = ws + off;
        off = (off + bytes + 255) & ~(size_t)255;
        return p;
    };
    int*    histA    = (int*)   carve((size_t)total * sizeof(int));          // 200 KB
    int*    coarsePtr= (int*)   carve((size_t)(nc + 1) * sizeof(int));
    uint*   epA      = (uint*)  carve((size_t)E * sizeof(uint));             // 6.4 MB
    uint*   ep       = (uint*)  carve((size_t)E * sizeof(uint));             // 6.4 MB
    int*    nodeptr  = (int*)   carve((size_t)(nc * CWID + 1) * sizeof(int));// 401 KB
    ushort* feat_b   = (ushort*)carve((size_t)N * D * sizeof(ushort));       // 25.6 MB
    ushort* Wc       = (ushort*)carve((size_t)D * KDIM * sizeof(ushort));

    const int nFeat8 = N * D / 8;            // 1.6M
    const int nbF = (nFeat8 + 255) / 256;    // 6250

    k_prep_hist<<<nbF + 128 + GFILL, 256, 0, stream>>>(
        feat, Wself, Wneigh, dst, feat_b, Wc, histA, nbF, nFeat8, E, chunk, nc);

    k_scan<<<1, 1024, 0, stream>>>(histA, coarsePtr, total, E);

    k_fillA<<<GFILL, 256, 0, stream>>>(src, dst, histA, epA, E, chunk, nc);

    k_fineB<<<nc, 256, 0, stream>>>(epA, coarsePtr, ep, nodeptr, nc);

    sage_fused<<<nb, 256, 0, stream>>>(feat_b, nodeptr, ep, (const short*)Wc, out, N);
}